// Round 1
// baseline (152.991 us; speedup 1.0000x reference)
//
#include <hip/hip_runtime.h>
#include <hip/hip_bf16.h>
#include <stdint.h>

typedef __attribute__((ext_vector_type(8))) __bf16 bf16x8;
typedef __attribute__((ext_vector_type(4))) float f32x4;

#define B_  2
#define H_  16
#define S_  2048
#define D_  128
#define BH_ (B_*H_)

__device__ __forceinline__ uint32_t f2bf1(float f){
  uint32_t u = __builtin_bit_cast(uint32_t, f);
  return (u + 0x7fffu + ((u >> 16) & 1u)) >> 16;   // RNE fp32 -> bf16
}
__device__ __forceinline__ uint32_t pk2(float a, float b){
  return f2bf1(a) | (f2bf1(b) << 16);
}

// ---------- pre-pass 1: K fp32 -> bf16, layout unchanged [bh][kv][d] ----------
__global__ void k_cvt(const float* __restrict__ in, unsigned short* __restrict__ out, int n4){
  int i = blockIdx.x * blockDim.x + threadIdx.x;
  int stride = gridDim.x * blockDim.x;
  for (; i < n4; i += stride){
    float4 f = ((const float4*)in)[i];
    ushort4 o;
    o.x = (unsigned short)f2bf1(f.x);
    o.y = (unsigned short)f2bf1(f.y);
    o.z = (unsigned short)f2bf1(f.z);
    o.w = (unsigned short)f2bf1(f.w);
    ((ushort4*)out)[i] = o;
  }
}

// ---------- pre-pass 2: V fp32 [bh][kv][d] -> Vt bf16 [bh][d][kv] ----------
__global__ void v_trans(const float* __restrict__ V, unsigned short* __restrict__ Vt){
  __shared__ __attribute__((aligned(16))) unsigned short t[64*68]; // pad 68 vs bank stride
  const int kv0 = blockIdx.x * 64, d0 = blockIdx.y * 64, bh = blockIdx.z;
  const int tid = threadIdx.x;
  const float* Vp = V + (size_t)bh * S_ * D_;
  for (int i = 0; i < 4; i++){
    int f = tid + i*256;            // 1024 float4 chunks of the 64x64 tile
    int kv = f >> 4, c4 = f & 15;
    float4 v = *(const float4*)(Vp + (size_t)(kv0+kv)*D_ + d0 + c4*4);
    *(uint2*)&t[kv*68 + c4*4] = make_uint2(pk2(v.x,v.y), pk2(v.z,v.w));
  }
  __syncthreads();
  unsigned short* Vo = Vt + (size_t)bh * D_ * S_;
  for (int i = 0; i < 4; i++){
    int g = tid + i*256;            // 1024 8B output chunks (4 bf16 along kv)
    int d = g >> 4, c = g & 15, kv = c*4;
    ushort4 o;
    o.x = t[(kv+0)*68 + d];
    o.y = t[(kv+1)*68 + d];
    o.z = t[(kv+2)*68 + d];
    o.w = t[(kv+3)*68 + d];
    *(ushort4*)(Vo + (size_t)(d0+d)*S_ + kv0 + kv) = o;
  }
}

// ---------- main flash-attention kernel ----------
// 4 waves x 16 q-rows = QBLK 64 per block; KVBLK 64; causal.
// Swapped QK^T: S^T = mfma(A=K_tile, B=Q^T) -> lane holds scores for q = lane&15.
// P round-trips through per-wave LDS to become the PV A-fragment.
__global__ __launch_bounds__(256, 2)
void attn_fwd(const float* __restrict__ Q, const unsigned short* __restrict__ Kb,
              const unsigned short* __restrict__ Vt, float* __restrict__ Out){
  __shared__ __attribute__((aligned(16))) unsigned short Klds[64*128]; // [kv][d] swz ^((kv&7)<<4)
  __shared__ __attribute__((aligned(16))) unsigned short Vlds[128*64]; // [d][kv] swz ^((d&7)<<4)
  __shared__ __attribute__((aligned(16))) unsigned short Plds[4][16*64]; // per-wave [q][kv] swz ^((q&7)<<4)
  __shared__ __attribute__((aligned(16))) float Flds[4][16];           // per-wave fac / l broadcast

  const int q0   = ((int)gridDim.x - 1 - (int)blockIdx.x) * 64; // heavy blocks first
  const int bh   = blockIdx.y;
  const int tid  = threadIdx.x;
  const int wave = tid >> 6, lane = tid & 63;
  const int ql   = lane & 15, hi = lane >> 4;      // hi = 0..3
  const int wq0  = q0 + wave*16;
  const int nt   = (q0 >> 6) + 1;
  const float scale = 0.08838834764831845f;        // 1/sqrt(128)

  // --- Q fragments (B-operand of swapped QK^T): Q[wq0+ql][ks*32 + hi*8 + j], j=0..7
  uint4 qf[4];
  {
    const float* Qp = Q + ((size_t)bh * S_ + (wq0 + ql)) * D_;
    #pragma unroll
    for (int ks = 0; ks < 4; ks++){
      float4 a = *(const float4*)(Qp + ks*32 + hi*8);
      float4 b = *(const float4*)(Qp + ks*32 + hi*8 + 4);
      qf[ks] = make_uint4(pk2(a.x,a.y), pk2(a.z,a.w), pk2(b.x,b.y), pk2(b.z,b.w));
    }
  }

  f32x4 o[8];
  #pragma unroll
  for (int nb = 0; nb < 8; nb++) o[nb] = (f32x4)(0.f);
  float m_run = -INFINITY, l_run = 0.f;

  const unsigned short* Kg = Kb + (size_t)bh * S_ * D_;
  const unsigned short* Vg = Vt + (size_t)bh * D_ * S_;

  for (int t = 0; t < nt; ++t){
    const int k0 = t * 64;

    // ---- stage K (64x128 bf16) and Vt (128x64 bf16) tiles, swizzled ----
    #pragma unroll
    for (int i = 0; i < 4; i++){
      int f = tid + i*256;                 // 1024 x 16B chunks
      int r = f >> 4, off = f & 15;        // kv row, 16B chunk in row
      uint4 v = *(const uint4*)(Kg + (size_t)(k0 + r)*D_ + off*8);
      int byte = (r*256 + off*16) ^ ((r & 7) << 4);
      *(uint4*)((char*)Klds + byte) = v;
    }
    #pragma unroll
    for (int i = 0; i < 4; i++){
      int f = tid + i*256;                 // 1024 x 16B chunks
      int r = f >> 3, off = f & 7;         // d row (128B each)
      uint4 v = *(const uint4*)(Vg + (size_t)r*S_ + k0 + off*8);
      int byte = (r*128 + off*16) ^ ((r & 7) << 4);
      *(uint4*)((char*)Vlds + byte) = v;
    }
    __syncthreads();

    // ---- swapped QK^T: sa[mb][r] = S^T[kv = mb*16+hi*4+r][q = ql] ----
    f32x4 sa[4];
    #pragma unroll
    for (int mb = 0; mb < 4; mb++){
      sa[mb] = (f32x4)(0.f);
      const int row = ql + mb*16;
      #pragma unroll
      for (int ks = 0; ks < 4; ks++){
        int byte = (row*256 + ks*64 + hi*16) ^ ((row & 7) << 4);
        bf16x8 kf = *(const bf16x8*)((const char*)Klds + byte);
        sa[mb] = __builtin_amdgcn_mfma_f32_16x16x32_bf16(
                    kf, __builtin_bit_cast(bf16x8, qf[ks]), sa[mb], 0, 0, 0);
      }
    }

    // ---- online softmax (per q-row, lane-local + 2 shfl_xor) ----
    float p[16];
    float pm = -INFINITY;
    const bool diag = (t == nt - 1);
    const int q_abs = wq0 + ql;
    #pragma unroll
    for (int mb = 0; mb < 4; mb++){
      #pragma unroll
      for (int r = 0; r < 4; r++){
        float s = sa[mb][r] * scale;
        int kv = k0 + mb*16 + hi*4 + r;
        if (diag && kv > q_abs) s = -1e30f;
        p[mb*4 + r] = s;
        pm = fmaxf(pm, s);
      }
    }
    pm = fmaxf(pm, __shfl_xor(pm, 16));
    pm = fmaxf(pm, __shfl_xor(pm, 32));
    float m_new = fmaxf(m_run, pm);
    float fac = __expf(m_run - m_new);
    m_run = m_new;
    float rs = 0.f;
    #pragma unroll
    for (int i = 0; i < 16; i++){ p[i] = __expf(p[i] - m_new); rs += p[i]; }
    rs += __shfl_xor(rs, 16);
    rs += __shfl_xor(rs, 32);
    l_run = l_run * fac + rs;

    // P -> LDS (bf16, per-wave region), packed b64 writes
    #pragma unroll
    for (int mb = 0; mb < 4; mb++){
      uint32_t lo  = pk2(p[mb*4+0], p[mb*4+1]);
      uint32_t hi2 = pk2(p[mb*4+2], p[mb*4+3]);
      int byte = (ql*128 + mb*32 + hi*8) ^ ((ql & 7) << 4);
      *(uint2*)((char*)&Plds[wave][0] + byte) = make_uint2(lo, hi2);
    }
    if (hi == 0) Flds[wave][ql] = fac;
    __syncthreads();

    // ---- rescale O by fac (broadcast via LDS: rows q = hi*4+r) ----
    f32x4 fv = *(const f32x4*)&Flds[wave][hi*4];
    #pragma unroll
    for (int nb = 0; nb < 8; nb++) o[nb] *= fv;

    // ---- PV: O[q][d] += P[q][kv] * V[kv][d] ----
    #pragma unroll
    for (int ks = 0; ks < 2; ks++){
      int pb = (ql*128 + ks*64 + hi*16) ^ ((ql & 7) << 4);
      bf16x8 pf = *(const bf16x8*)((const char*)&Plds[wave][0] + pb);
      #pragma unroll
      for (int nb = 0; nb < 8; nb++){
        int d = ql + nb*16;
        int vb = (d*128 + ks*64 + hi*16) ^ ((d & 7) << 4);
        bf16x8 vf = *(const bf16x8*)((const char*)Vlds + vb);
        o[nb] = __builtin_amdgcn_mfma_f32_16x16x32_bf16(pf, vf, o[nb], 0, 0, 0);
      }
    }
    __syncthreads();
  }

  // ---- epilogue: divide by l (broadcast per-row), write fp32 output ----
  if (hi == 0) Flds[wave][ql] = l_run;
  __syncthreads();
  f32x4 lv = *(const f32x4*)&Flds[wave][hi*4];
  float rl[4];
  #pragma unroll
  for (int r = 0; r < 4; r++) rl[r] = 1.f / lv[r];

  float* Op = Out + ((size_t)bh * S_ + wq0) * D_;
  #pragma unroll
  for (int nb = 0; nb < 8; nb++){
    #pragma unroll
    for (int r = 0; r < 4; r++){
      Op[(size_t)(hi*4 + r)*D_ + nb*16 + ql] = o[nb][r] * rl[r];
    }
  }
}

extern "C" void kernel_launch(void* const* d_in, const int* in_sizes, int n_in,
                              void* d_out, int out_size, void* d_ws, size_t ws_size,
                              hipStream_t stream){
  const float* Q = (const float*)d_in[0];
  const float* K = (const float*)d_in[1];
  const float* V = (const float*)d_in[2];
  float* Out = (float*)d_out;

  // workspace: Kbf16 (16 MB) then Vt bf16 (16 MB)
  unsigned short* Kb = (unsigned short*)d_ws;
  unsigned short* Vt = Kb + (size_t)BH_ * S_ * D_;

  k_cvt<<<2048, 256, 0, stream>>>(K, Kb, BH_*S_*D_/4);
  v_trans<<<dim3(S_/64, D_/64, BH_), 256, 0, stream>>>(V, Vt);
  attn_fwd<<<dim3(S_/64, BH_), 256, 0, stream>>>(Q, Kb, Vt, Out);
}